// Round 3
// baseline (194.228 us; speedup 1.0000x reference)
//
#include <hip/hip_runtime.h>
#include <math.h>

namespace {

constexpr int kS = 26;
constexpr int kA = 5;
constexpr int kP = kS * kS * kA;   // 3380
constexpr int kM = 30;
constexpr int kB = 128;
constexpr float kCW = 16.0f;       // IM / S
constexpr int kT = 256;            // threads/block (4 waves)
constexpr int kChunks = 4;
constexpr int kChunk = kP / kChunks;  // 845
constexpr int kNP = 4;                // ceil(845/256)
constexpr int kGrid = kChunks * kB;   // 512 blocks

// ws layout: keys[kB*kM] u64 | accum[3] f32 | counter u32  (all zeroed per call)
constexpr size_t kKeyN = (size_t)kB * kM;       // 3840
constexpr size_t kKeyBytes = kKeyN * 8;         // 30720
constexpr size_t kZeroBytes = kKeyBytes + 16;

__device__ __forceinline__ float sig(float x) { return 1.0f / (1.0f + expf(-x)); }

// ---- DPP wave64 reductions (VALU pipe; no LDS traffic) ----
// row_shr:1/2/4/8 then row_bcast15/31; bound_ctrl=1 -> OOR lanes read 0
// (identity for unsigned max over keys>=2^63 ... and for f32 sum). Result in lane 63.
template <int CTRL>
__device__ __forceinline__ void dpp_max_u64(unsigned& hi, unsigned& lo) {
  const unsigned h2 = (unsigned)__builtin_amdgcn_update_dpp(0, (int)hi, CTRL, 0xF, 0xF, true);
  const unsigned l2 = (unsigned)__builtin_amdgcn_update_dpp(0, (int)lo, CTRL, 0xF, 0xF, true);
  const unsigned long long a = ((unsigned long long)hi << 32) | lo;
  const unsigned long long b = ((unsigned long long)h2 << 32) | l2;
  if (b > a) { hi = h2; lo = l2; }
}
__device__ __forceinline__ unsigned long long wave_max_u64(unsigned hi, unsigned lo) {
  dpp_max_u64<0x111>(hi, lo);  // row_shr:1
  dpp_max_u64<0x112>(hi, lo);  // row_shr:2
  dpp_max_u64<0x114>(hi, lo);  // row_shr:4
  dpp_max_u64<0x118>(hi, lo);  // row_shr:8
  dpp_max_u64<0x142>(hi, lo);  // row_bcast:15
  dpp_max_u64<0x143>(hi, lo);  // row_bcast:31
  return ((unsigned long long)hi << 32) | lo;  // valid in lane 63
}
template <int CTRL>
__device__ __forceinline__ float dpp_add(float v) {
  const int o = __builtin_amdgcn_update_dpp(0, __float_as_int(v), CTRL, 0xF, 0xF, true);
  return v + __int_as_float(o);
}
__device__ __forceinline__ float wave_sum(float v) {
  v = dpp_add<0x111>(v);
  v = dpp_add<0x112>(v);
  v = dpp_add<0x114>(v);
  v = dpp_add<0x118>(v);
  v = dpp_add<0x142>(v);
  v = dpp_add<0x143>(v);
  return v;  // valid in lane 63
}

__global__ __launch_bounds__(kT) void yolo_loss(
    const float* __restrict__ pred, const float* __restrict__ targ,
    const float* __restrict__ anch, float* __restrict__ out,
    unsigned long long* __restrict__ keys, float* __restrict__ accum,
    unsigned* __restrict__ counter) {
  __shared__ float s_gx1[kM], s_gx2[kM], s_gy1[kM], s_gy2[kM], s_ga[kM];
  __shared__ int s_valid[kM];
  __shared__ float s_anc[2 * kA];
  __shared__ float s_red[4][3];
  __shared__ unsigned s_ticket;
  __shared__ int s_idx[kB * kM];            // finale: responsible idx per (b,m)
  __shared__ unsigned char s_vf[kB * kM];   // finale: valid flags

  const int tid = threadIdx.x;
  const int lane = tid & 63;
  const int wid = tid >> 6;
  const int c = blockIdx.x;
  const int b = blockIdx.y;

  if (tid < 2 * kA) s_anc[tid] = anch[tid];
  if (tid < kM) {
    const float t0 = targ[b * kM * 5 + tid * 5 + 0];
    const float t1 = targ[b * kM * 5 + tid * 5 + 1];
    const float t2 = targ[b * kM * 5 + tid * 5 + 2];
    const float t3 = targ[b * kM * 5 + tid * 5 + 3];
    const float t4 = targ[b * kM * 5 + tid * 5 + 4];
    const float gxc = t0 + t2 * 0.5f;
    const float gyc = t1 + t3 * 0.5f;
    const float gw = t2 - t0;  // faithful to source
    const float gh = t3 * t1;  // faithful to source
    s_gx1[tid] = gxc - gw * 0.5f;
    s_gx2[tid] = gxc + gw * 0.5f;
    s_gy1[tid] = gyc - gh * 0.5f;
    s_gy2[tid] = gyc + gh * 0.5f;
    s_ga[tid] = gw * gh;
    s_valid[tid] = (t4 == 1.0f) ? 1 : 0;
  }
  __syncthreads();

  // ---- decode this thread's <=4 boxes into registers ----
  const int p0 = c * kChunk;
  const int pend = p0 + kChunk;
  float px1[kNP], px2[kNP], py1[kNP], py2[kNP], ap[kNP], cc[kNP];
  bool on[kNP];
#pragma unroll
  for (int i = 0; i < kNP; ++i) {
    const int p = p0 + tid + i * kT;
    on[i] = (p < pend);
    px1[i] = 0.f; px2[i] = 0.f; py1[i] = 0.f; py2[i] = 0.f; ap[i] = 0.f; cc[i] = 0.f;
    if (on[i]) {
      const float* pp = pred + ((size_t)b * kP + p) * 25;
      const float s0 = sig(pp[0]);
      const float s1 = sig(pp[1]);
      const float s2 = sig(pp[2]) * 0.5f;
      const float s3 = sig(pp[3]) * 0.5f;
      cc[i] = sig(pp[4]);
      const int a = p % kA;
      const int gx = (p / kA) % kS;
      const int gy = p / (kA * kS);
      const float bx = (s0 + (float)gx) * kCW;
      const float by = (s1 + (float)gy) * kCW;
      const float bw = expf(s2) * s_anc[2 * a + 0] * kCW;
      const float bh = expf(s3) * s_anc[2 * a + 1] * kCW;
      const float hw = bw * 0.5f, hh = bh * 0.5f;
      px1[i] = bx - hw;  // exactly pbox[...,0] -+ pbox[...,2]/2
      px2[i] = bx + hw;
      py1[i] = by - hh;
      py2[i] = by + hh;
      ap[i] = bw * bh;
    }
  }

  // ---- m-outer loop: per-lane argmax in regs, one DPP reduce + atomic per m ----
  unsigned objm = 0;
  for (int m = 0; m < kM; ++m) {
    if (!s_valid[m]) continue;  // wave-uniform
    const float gx1 = s_gx1[m], gx2 = s_gx2[m];
    const float gy1 = s_gy1[m], gy2 = s_gy2[m];
    const float ga = s_ga[m];
    float best = -INFINITY;
    int bi = 0;
#pragma unroll
    for (int i = 0; i < kNP; ++i) {
      if (!on[i]) continue;
      float dx = fminf(gx2, px2[i]) - fmaxf(gx1, px1[i]);
      float dy = fminf(gy2, py2[i]) - fmaxf(gy1, py1[i]);
      dx = fmaxf(dx, 0.0f);
      dy = fmaxf(dy, 0.0f);
      const float inter = dx * dy;
      const float iou = inter / (ga + ap[i] - inter + 1e-9f);
      if (iou > 0.6f) objm |= 1u << i;
      if (iou > best) { best = iou; bi = p0 + tid + i * kT; }  // p increasing: first-tie kept
    }
    // monotone pack; +-0 collapse to 0x80000000 (== semantics); ~p => smaller p wins ties
    const unsigned u = __float_as_uint(best);
    const unsigned hi = (best >= 0.0f) ? (u | 0x80000000u) : ~u;
    const unsigned lo = 0xFFFFFFFFu - (unsigned)bi;
    const unsigned long long k = wave_max_u64(hi, lo);
    if (lane == 63) atomicMax(&keys[(size_t)b * kM + m], k);
  }

  // ---- conf terms ----
  float objt = 0.0f, noob = 0.0f;
#pragma unroll
  for (int i = 0; i < kNP; ++i) {
    if (!on[i]) continue;
    if (objm & (1u << i)) {
      const float d = cc[i] - 1.0f;
      objt += d * d;
    } else {
      noob += cc[i] * cc[i];
    }
  }
  objt = wave_sum(objt);
  noob = wave_sum(noob);
  if (lane == 63) {
    s_red[wid][0] = objt;
    s_red[wid][1] = noob;
  }
  __syncthreads();
  if (tid == 0) {
    atomicAdd(&accum[0], s_red[0][0] + s_red[1][0] + s_red[2][0] + s_red[3][0]);
    atomicAdd(&accum[1], s_red[0][1] + s_red[1][1] + s_red[2][1] + s_red[3][1]);
  }

  // ---- last-block ticket ----
  __threadfence();
  __syncthreads();
  if (tid == 0) s_ticket = atomicAdd(counter, 1u);
  __syncthreads();
  if (s_ticket != (unsigned)(kGrid - 1)) return;
  __threadfence();

  // ---- finale (one block): loc loss + combine ----
  for (int i = tid; i < kB * kM; i += kT) {
    const unsigned long long k = atomicMax(&keys[i], 0ull);  // coherent read
    s_idx[i] = (k == 0ull) ? 0 : (int)(0xFFFFFFFFu - (unsigned)(k & 0xFFFFFFFFull));
    const int bb = i / kM;
    const int mm = i - bb * kM;
    s_vf[i] = (targ[(size_t)bb * kM * 5 + mm * 5 + 4] == 1.0f) ? 1 : 0;
  }
  __syncthreads();

  float loc = 0.0f;
  for (int i = tid; i < kB * kM; i += kT) {
    if (!s_vf[i]) continue;
    const int bb = i / kM;
    const int mm = i - bb * kM;
    const int idx = s_idx[i];
    bool dead = false;  // last-valid-m-wins dedup (matches scatter overwrite order)
    for (int j = mm + 1; j < kM; ++j) {
      if (s_vf[bb * kM + j] && s_idx[bb * kM + j] == idx) { dead = true; break; }
    }
    if (dead) continue;
    const float* tt = targ + (size_t)bb * kM * 5 + mm * 5;
    const float t0 = tt[0], t1 = tt[1], t2 = tt[2], t3 = tt[3];
    const float gxc = t0 + t2 * 0.5f;
    const float gyc = t1 + t3 * 0.5f;
    const int ra = idx % kA;
    const int rw = (idx / kA) % kS;
    const int rh = idx / (kA * kS);
    const float tx = (gxc - (float)rw * kCW) / kCW;
    const float ty = (gyc - (float)rh * kCW) / kCW;
    const float tw = logf((t2 / kCW) / s_anc[2 * ra + 0]);
    const float th = logf((t3 / kCW) / s_anc[2 * ra + 1]);
    const float* pp = pred + ((size_t)bb * kP + idx) * 25;
    const float d0 = sig(pp[0]) - tx;
    const float d1 = sig(pp[1]) - ty;
    const float d2 = sig(pp[2]) * 0.5f - tw;
    const float d3 = sig(pp[3]) * 0.5f - th;
    loc += d0 * d0 + d1 * d1 + d2 * d2 + d3 * d3;
  }
  loc = wave_sum(loc);
  if (lane == 63) s_red[wid][2] = loc;
  __syncthreads();
  if (tid == 0) {
    const float l = s_red[0][2] + s_red[1][2] + s_red[2][2] + s_red[3][2];
    const float a0 = atomicAdd(&accum[0], 0.0f);  // coherent read
    const float a1 = atomicAdd(&accum[1], 0.0f);
    const float loss_conf = (a0 + 0.5f * a1) / (float)kB;
    const float loss_loc = 5.0f * l / (float)kB;
    out[0] = loss_loc + loss_conf;
    out[1] = loss_loc;
    out[2] = loss_conf;
  }
}

}  // namespace

extern "C" void kernel_launch(void* const* d_in, const int* in_sizes, int n_in,
                              void* d_out, int out_size, void* d_ws, size_t ws_size,
                              hipStream_t stream) {
  const float* pred = (const float*)d_in[0];
  const float* targ = (const float*)d_in[1];
  const float* anch = (const float*)d_in[2];
  float* out = (float*)d_out;
  unsigned long long* keys = (unsigned long long*)d_ws;
  float* accum = (float*)((char*)d_ws + kKeyBytes);
  unsigned* counter = (unsigned*)((char*)d_ws + kKeyBytes + 12);

  hipMemsetAsync(d_ws, 0, kZeroBytes, stream);
  yolo_loss<<<dim3(kChunks, kB), kT, 0, stream>>>(pred, targ, anch, out, keys, accum, counter);
}